// Round 1
// baseline (484.924 us; speedup 1.0000x reference)
//
#include <hip/hip_runtime.h>
#include <math.h>

#define HDIM 2048
#define THREADS 256
#define VEC (HDIM / (THREADS * 4))  // 2 float4 per thread per row

__global__ __launch_bounds__(THREADS)
void altup_kernel(const float* __restrict__ hs,     // [4, T, H]
                  const float* __restrict__ act,    // [T, H]
                  const float* __restrict__ rnw,    // [H]
                  const float* __restrict__ mrw,    // [4, H]
                  const float* __restrict__ pw,     // [16, 4]
                  const float* __restrict__ cw,     // [4, 4]
                  const float* __restrict__ scale,  // [H]
                  float* __restrict__ out,          // [4, T, H]
                  int T)
{
    const int t = blockIdx.x;
    const int tid = threadIdx.x;
    const size_t row = (size_t)t * HDIM;
    const size_t plane = (size_t)T * HDIM;

    const float4* hs0p = (const float4*)(hs + row);
    const float4* actp = (const float4*)(act + row);
    const float4* wp   = (const float4*)rnw;
    const float4* mrp  = (const float4*)mrw;

    // ---- phase 1: reductions for both modality() calls ----
    float4 x0v[VEC], av[VEC];
    float acc[10];  // [0]=ssq(hs0), [1..4]=dot(hs0*w, mrw[n]), [5]=ssq(act), [6..9]=dot(act*w, mrw[n])
    #pragma unroll
    for (int k = 0; k < 10; ++k) acc[k] = 0.f;

    #pragma unroll
    for (int v = 0; v < VEC; ++v) {
        const int idx = tid + v * THREADS;
        const float4 x  = hs0p[idx];
        const float4 a  = actp[idx];
        const float4 ww = wp[idx];
        x0v[v] = x; av[v] = a;
        acc[0] += x.x*x.x + x.y*x.y + x.z*x.z + x.w*x.w;
        acc[5] += a.x*a.x + a.y*a.y + a.z*a.z + a.w*a.w;
        const float xwx = x.x*ww.x, xwy = x.y*ww.y, xwz = x.z*ww.z, xww = x.w*ww.w;
        const float awx = a.x*ww.x, awy = a.y*ww.y, awz = a.z*ww.z, aww = a.w*ww.w;
        #pragma unroll
        for (int n = 0; n < 4; ++n) {
            const float4 r = mrp[n * (HDIM/4) + idx];
            acc[1+n] += xwx*r.x + xwy*r.y + xwz*r.z + xww*r.w;
            acc[6+n] += awx*r.x + awy*r.y + awz*r.z + aww*r.w;
        }
    }

    // wave shuffle reduce, then cross-wave via LDS
    __shared__ float part[THREADS/64][10];
    const int lane = tid & 63, wv = tid >> 6;
    #pragma unroll
    for (int k = 0; k < 10; ++k) {
        float s = acc[k];
        #pragma unroll
        for (int off = 32; off >= 1; off >>= 1) s += __shfl_down(s, off, 64);
        if (lane == 0) part[wv][k] = s;
    }
    __syncthreads();
    float tot[10];
    #pragma unroll
    for (int k = 0; k < 10; ++k)
        tot[k] = part[0][k] + part[1][k] + part[2][k] + part[3][k];

    // ---- tiny per-token math (computed redundantly by all threads) ----
    const float invH = 1.0f / HDIM;
    const float rs0 = rsqrtf(tot[0] * invH + 1e-6f) * invH;
    const float rsA = rsqrtf(tot[5] * invH + 1e-6f) * invH;
    float m0[4], m2[4];
    #pragma unroll
    for (int n = 0; n < 4; ++n) {
        m0[n] = tanhf(tot[1+n] * rs0);
        m2[n] = tanhf(tot[6+n] * rsA);
    }
    float c[4][4], cc[4];
    #pragma unroll
    for (int j = 0; j < 4; ++j) {
        #pragma unroll
        for (int i = 0; i < 4; ++i) {
            const float* p = pw + (j*4 + i) * 4;   // prediction_w[j*N+i, n]
            c[j][i] = p[0]*m0[0] + p[1]*m0[1] + p[2]*m0[2] + p[3]*m0[3]
                    + (i == j ? 1.f : 0.f);        // + identity (pred += hs[j])
        }
        const float* q = cw + j*4;                 // correction_w[j, n]
        cc[j] = 1.f + q[0]*m2[0] + q[1]*m2[1] + q[2]*m2[2] + q[3]*m2[3];
    }

    // ---- phase 2: stream hs[1..3], combine, write 4 output planes ----
    const float4* h1p = (const float4*)(hs + plane + row);
    const float4* h2p = (const float4*)(hs + 2*plane + row);
    const float4* h3p = (const float4*)(hs + 3*plane + row);
    const float4* scp = (const float4*)scale;
    float4* o0 = (float4*)(out + row);
    float4* o1 = (float4*)(out + plane + row);
    float4* o2 = (float4*)(out + 2*plane + row);
    float4* o3 = (float4*)(out + 3*plane + row);

    #pragma unroll
    for (int v = 0; v < VEC; ++v) {
        const int idx = tid + v * THREADS;
        const float4 x1 = h1p[idx];
        const float4 x2 = h2p[idx];
        const float4 x3 = h3p[idx];
        const float4 sc = scp[idx];
        const float4 x0 = x0v[v];
        const float4 a  = av[v];
        float4 r0, r1, r2, r3;
        #define COMP(f) { \
            const float p0 = c[0][0]*x0.f + c[0][1]*x1.f + c[0][2]*x2.f + c[0][3]*x3.f; \
            const float p1 = c[1][0]*x0.f + c[1][1]*x1.f + c[1][2]*x2.f + c[1][3]*x3.f; \
            const float p2 = c[2][0]*x0.f + c[2][1]*x1.f + c[2][2]*x2.f + c[2][3]*x3.f; \
            const float p3 = c[3][0]*x0.f + c[3][1]*x1.f + c[3][2]*x2.f + c[3][3]*x3.f; \
            const float inn = a.f - p0; \
            r0.f = (p0 + inn*cc[0]) * sc.f; \
            r1.f = (p1 + inn*cc[1]) * sc.f; \
            r2.f = (p2 + inn*cc[2]) * sc.f; \
            r3.f = (p3 + inn*cc[3]) * sc.f; }
        COMP(x) COMP(y) COMP(z) COMP(w)
        #undef COMP
        o0[idx] = r0;
        o1[idx] = r1;
        o2[idx] = r2;
        o3[idx] = r3;
    }
}

extern "C" void kernel_launch(void* const* d_in, const int* in_sizes, int n_in,
                              void* d_out, int out_size, void* d_ws, size_t ws_size,
                              hipStream_t stream) {
    const float* hs  = (const float*)d_in[0];  // hidden_states [4,B,S,H]
    const float* act = (const float*)d_in[1];  // activated [B,S,H]
    const float* rnw = (const float*)d_in[2];  // router_norm_weight [H]
    const float* mrw = (const float*)d_in[3];  // modality_router_w [4,H]
    const float* pw  = (const float*)d_in[4];  // prediction_w [16,4]
    const float* cw  = (const float*)d_in[5];  // correction_w [4,4]
    const float* sc  = (const float*)d_in[6];  // correct_output_scale [H]
    float* out = (float*)d_out;

    const int T = in_sizes[1] / HDIM;          // B*S tokens
    altup_kernel<<<T, THREADS, 0, stream>>>(hs, act, rnw, mrw, pw, cw, sc, out, T);
}

// Round 2
// 469.071 us; speedup vs baseline: 1.0338x; 1.0338x over previous
//
#include <hip/hip_runtime.h>
#include <math.h>

#define HDIM 2048
#define THREADS 256
#define VEC (HDIM / (THREADS * 4))  // 2 float4-equivalents per thread per row

typedef float v4f __attribute__((ext_vector_type(4)));

__global__ __launch_bounds__(THREADS, 4)
void altup_kernel(const float* __restrict__ hs,     // [4, T, H]
                  const float* __restrict__ act,    // [T, H]
                  const float* __restrict__ rnw,    // [H]
                  const float* __restrict__ mrw,    // [4, H]
                  const float* __restrict__ pw,     // [16, 4]
                  const float* __restrict__ cw,     // [4, 4]
                  const float* __restrict__ scale,  // [H]
                  float* __restrict__ out,          // [4, T, H]
                  int T)
{
    const int t = blockIdx.x;
    const int tid = threadIdx.x;
    const size_t row = (size_t)t * HDIM;
    const size_t plane = (size_t)T * HDIM;

    const v4f* hs0p = (const v4f*)(hs + row);
    const v4f* actp = (const v4f*)(act + row);
    const v4f* wp   = (const v4f*)rnw;     // reused across all blocks -> cached
    const v4f* mrp  = (const v4f*)mrw;     // reused across all blocks -> cached

    // ---- phase 1: reductions for both modality() calls ----
    // Streamed rows (touch-once) use nontemporal loads to avoid L2 pollution.
    v4f x0v[VEC], av[VEC];
    float acc[10];  // [0]=ssq(hs0), [1..4]=dot(hs0*w,mrw[n]), [5]=ssq(act), [6..9]=dot(act*w,mrw[n])
    #pragma unroll
    for (int k = 0; k < 10; ++k) acc[k] = 0.f;

    #pragma unroll
    for (int v = 0; v < VEC; ++v) {
        const int idx = tid + v * THREADS;
        const v4f x  = __builtin_nontemporal_load(hs0p + idx);
        const v4f a  = __builtin_nontemporal_load(actp + idx);
        const v4f ww = wp[idx];
        x0v[v] = x; av[v] = a;
        acc[0] += x.x*x.x + x.y*x.y + x.z*x.z + x.w*x.w;
        acc[5] += a.x*a.x + a.y*a.y + a.z*a.z + a.w*a.w;
        const float xwx = x.x*ww.x, xwy = x.y*ww.y, xwz = x.z*ww.z, xww = x.w*ww.w;
        const float awx = a.x*ww.x, awy = a.y*ww.y, awz = a.z*ww.z, aww = a.w*ww.w;
        #pragma unroll
        for (int n = 0; n < 4; ++n) {
            const v4f r = mrp[n * (HDIM/4) + idx];
            acc[1+n] += xwx*r.x + xwy*r.y + xwz*r.z + xww*r.w;
            acc[6+n] += awx*r.x + awy*r.y + awz*r.z + aww*r.w;
        }
    }

    // ---- prefetch phase-2 streams BEFORE the reduction so their HBM
    // latency overlaps the shuffle/LDS reduction + tanh math ----
    const v4f* h1p = (const v4f*)(hs + plane + row);
    const v4f* h2p = (const v4f*)(hs + 2*plane + row);
    const v4f* h3p = (const v4f*)(hs + 3*plane + row);
    const v4f* scp = (const v4f*)scale;    // reused across all blocks -> cached
    v4f x1v[VEC], x2v[VEC], x3v[VEC], scv[VEC];
    #pragma unroll
    for (int v = 0; v < VEC; ++v) {
        const int idx = tid + v * THREADS;
        x1v[v] = __builtin_nontemporal_load(h1p + idx);
        x2v[v] = __builtin_nontemporal_load(h2p + idx);
        x3v[v] = __builtin_nontemporal_load(h3p + idx);
        scv[v] = scp[idx];
    }

    // ---- wave shuffle reduce, then cross-wave via LDS ----
    __shared__ float part[THREADS/64][10];
    const int lane = tid & 63, wv = tid >> 6;
    #pragma unroll
    for (int k = 0; k < 10; ++k) {
        float s = acc[k];
        #pragma unroll
        for (int off = 32; off >= 1; off >>= 1) s += __shfl_down(s, off, 64);
        if (lane == 0) part[wv][k] = s;
    }
    __syncthreads();
    float tot[10];
    #pragma unroll
    for (int k = 0; k < 10; ++k)
        tot[k] = part[0][k] + part[1][k] + part[2][k] + part[3][k];

    // ---- tiny per-token math (computed redundantly by all threads) ----
    const float invH = 1.0f / HDIM;
    const float rs0 = rsqrtf(tot[0] * invH + 1e-6f) * invH;
    const float rsA = rsqrtf(tot[5] * invH + 1e-6f) * invH;
    float m0[4], m2[4];
    #pragma unroll
    for (int n = 0; n < 4; ++n) {
        m0[n] = tanhf(tot[1+n] * rs0);
        m2[n] = tanhf(tot[6+n] * rsA);
    }
    float c[4][4], cc[4];
    #pragma unroll
    for (int j = 0; j < 4; ++j) {
        #pragma unroll
        for (int i = 0; i < 4; ++i) {
            const float* p = pw + (j*4 + i) * 4;   // prediction_w[j*N+i, n]
            c[j][i] = p[0]*m0[0] + p[1]*m0[1] + p[2]*m0[2] + p[3]*m0[3]
                    + (i == j ? 1.f : 0.f);        // + identity (pred += hs[j])
        }
        const float* q = cw + j*4;                 // correction_w[j, n]
        cc[j] = 1.f + q[0]*m2[0] + q[1]*m2[1] + q[2]*m2[2] + q[3]*m2[3];
    }

    // ---- phase 2: combine, nontemporal-write 4 output planes ----
    float* o0 = out + row;
    float* o1 = out + plane + row;
    float* o2 = out + 2*plane + row;
    float* o3 = out + 3*plane + row;

    #pragma unroll
    for (int v = 0; v < VEC; ++v) {
        const int idx = tid + v * THREADS;
        const v4f x0 = x0v[v];
        const v4f a  = av[v];
        const v4f x1 = x1v[v];
        const v4f x2 = x2v[v];
        const v4f x3 = x3v[v];
        const v4f sc = scv[v];
        v4f r0, r1, r2, r3;
        #define COMP(f) { \
            const float p0 = c[0][0]*x0.f + c[0][1]*x1.f + c[0][2]*x2.f + c[0][3]*x3.f; \
            const float p1 = c[1][0]*x0.f + c[1][1]*x1.f + c[1][2]*x2.f + c[1][3]*x3.f; \
            const float p2 = c[2][0]*x0.f + c[2][1]*x1.f + c[2][2]*x2.f + c[2][3]*x3.f; \
            const float p3 = c[3][0]*x0.f + c[3][1]*x1.f + c[3][2]*x2.f + c[3][3]*x3.f; \
            const float inn = a.f - p0; \
            r0.f = (p0 + inn*cc[0]) * sc.f; \
            r1.f = (p1 + inn*cc[1]) * sc.f; \
            r2.f = (p2 + inn*cc[2]) * sc.f; \
            r3.f = (p3 + inn*cc[3]) * sc.f; }
        COMP(x) COMP(y) COMP(z) COMP(w)
        #undef COMP
        __builtin_nontemporal_store(r0, (v4f*)(o0) + idx);
        __builtin_nontemporal_store(r1, (v4f*)(o1) + idx);
        __builtin_nontemporal_store(r2, (v4f*)(o2) + idx);
        __builtin_nontemporal_store(r3, (v4f*)(o3) + idx);
    }
}

extern "C" void kernel_launch(void* const* d_in, const int* in_sizes, int n_in,
                              void* d_out, int out_size, void* d_ws, size_t ws_size,
                              hipStream_t stream) {
    const float* hs  = (const float*)d_in[0];  // hidden_states [4,B,S,H]
    const float* act = (const float*)d_in[1];  // activated [B,S,H]
    const float* rnw = (const float*)d_in[2];  // router_norm_weight [H]
    const float* mrw = (const float*)d_in[3];  // modality_router_w [4,H]
    const float* pw  = (const float*)d_in[4];  // prediction_w [16,4]
    const float* cw  = (const float*)d_in[5];  // correction_w [4,4]
    const float* sc  = (const float*)d_in[6];  // correct_output_scale [H]
    float* out = (float*)d_out;

    const int T = in_sizes[1] / HDIM;          // B*S tokens
    altup_kernel<<<T, THREADS, 0, stream>>>(hs, act, rnw, mrw, pw, cw, sc, out, T);
}